// Round 7
// baseline (279.657 us; speedup 1.0000x reference)
//
#include <hip/hip_runtime.h>

// N=4194304 rows, C=8. Output: scalar mean(ce_loss * value).
// MEASUREMENT ROUND: stage1 is idempotent (partials[b] = ...), launched 4x.
// Total = overhead + 4*K + gaps -> Delta vs 195us baseline = 3*(K+gap).
//   Model A (kernel ~50us): expect ~345us total.
//   Model B (kernel ~25us, overhead ~170): expect ~270us total.
// History: R1 atomics serialized; R2-R5 four structures all 200+-4us;
// R6 nontemporal loads -5us (kept).

#define N_ROWS 4194304
#define TPB 256
#define GRID 2048
#define RPT (N_ROWS / (GRID * TPB))   // 8 rows per thread
#define BATCH 4

typedef float vf4 __attribute__((ext_vector_type(4)));

__device__ __forceinline__ float row_contrib(vf4 v0, vf4 v1, int t) {
    // inv(T_COV) = [[2.4, 1.6],[1.6, 2.4]];  inv(F_COV) = [[10.303,-9.697],[...]]
    float m1 = v0.x, m2 = -INFINITY;
    float xs[7] = {v0.y, v0.z, v0.w, v1.x, v1.y, v1.z, v1.w};
    #pragma unroll
    for (int i = 0; i < 7; ++i) {
        float xi = xs[i];
        float hi = fmaxf(xi, m1);
        float lo = fminf(xi, m1);
        m2 = fmaxf(m2, lo);
        m1 = hi;
    }

    float s = __expf(v0.x - m1) + __expf(v0.y - m1) +
              __expf(v0.z - m1) + __expf(v0.w - m1) +
              __expf(v1.x - m1) + __expf(v1.y - m1) +
              __expf(v1.z - m1) + __expf(v1.w - m1);

    float xt = v0.x;
    xt = (t == 1) ? v0.y : xt;
    xt = (t == 2) ? v0.z : xt;
    xt = (t == 3) ? v0.w : xt;
    xt = (t == 4) ? v1.x : xt;
    xt = (t == 5) ? v1.y : xt;
    xt = (t == 6) ? v1.z : xt;
    xt = (t == 7) ? v1.w : xt;

    float inv_s = 1.0f / s;
    float p_t   = __expf(xt - m1) * inv_s;
    float ce    = (m1 - xt) + __logf(s);     // -logp[target]

    bool  is_t  = (xt == m1);                // p_t is the max prob
    float p_neg = is_t ? __expf(m2 - m1) * inv_s : inv_s;  // max = exp(0)/s

    float aC = is_t ? 2.4f : 10.30303030303030f;
    float bC = is_t ? 1.6f : -9.69696969696970f;
    float dx = p_t   - (is_t ? 0.5f : 0.3f);
    float dy = p_neg - (is_t ? 0.5f : 0.15f);

    float q = aC * (dx * dx + dy * dy) + 2.0f * bC * dx * dy;
    return ce * __expf(-0.5f * q);
}

// Stage 1 (idempotent): grid-stride, 8 rows/thread batch-4, NT loads,
// per-block partial written with '=' to d_ws.
__global__ __launch_bounds__(TPB) void coga_stage1(
    const vf4* __restrict__ x4,
    const int* __restrict__ tgt,
    float* __restrict__ partials)
{
    const int tid    = blockIdx.x * TPB + threadIdx.x;
    const int stride = GRID * TPB;

    float acc = 0.0f;
    #pragma unroll
    for (int k = 0; k < RPT; k += BATCH) {
        vf4 a0[BATCH], a1[BATCH];
        int t[BATCH];
        #pragma unroll
        for (int j = 0; j < BATCH; ++j) {
            int row = tid + (k + j) * stride;
            a0[j] = __builtin_nontemporal_load(&x4[2 * (size_t)row]);
            a1[j] = __builtin_nontemporal_load(&x4[2 * (size_t)row + 1]);
            t[j]  = __builtin_nontemporal_load(&tgt[row]);
        }
        #pragma unroll
        for (int j = 0; j < BATCH; ++j)
            acc += row_contrib(a0[j], a1[j], t[j]);
    }

    #pragma unroll
    for (int off = 32; off > 0; off >>= 1)
        acc += __shfl_down(acc, off, 64);

    __shared__ float wsum[TPB / 64];
    int lane = threadIdx.x & 63;
    int wid  = threadIdx.x >> 6;
    if (lane == 0) wsum[wid] = acc;
    __syncthreads();

    if (threadIdx.x == 0) {
        float bs = 0.0f;
        #pragma unroll
        for (int w = 0; w < TPB / 64; ++w) bs += wsum[w];
        partials[blockIdx.x] = bs;
    }
}

// Stage 2: reduce GRID partials, write mean directly (no memset needed).
__global__ __launch_bounds__(1024) void coga_stage2(
    const float* __restrict__ partials,
    float* __restrict__ out)
{
    float s = 0.0f;
    for (int i = threadIdx.x; i < GRID; i += 1024)
        s += partials[i];

    #pragma unroll
    for (int off = 32; off > 0; off >>= 1)
        s += __shfl_down(s, off, 64);

    __shared__ float wsum[1024 / 64];
    int lane = threadIdx.x & 63;
    int wid  = threadIdx.x >> 6;
    if (lane == 0) wsum[wid] = s;
    __syncthreads();

    if (threadIdx.x == 0) {
        float bs = 0.0f;
        #pragma unroll
        for (int w = 0; w < 1024 / 64; ++w) bs += wsum[w];
        out[0] = bs * (1.0f / (float)N_ROWS);
    }
}

extern "C" void kernel_launch(void* const* d_in, const int* in_sizes, int n_in,
                              void* d_out, int out_size, void* d_ws, size_t ws_size,
                              hipStream_t stream) {
    const float* x   = (const float*)d_in[0];
    const int*   tgt = (const int*)d_in[1];
    float*       out = (float*)d_out;
    float* partials  = (float*)d_ws;   // 2048 floats << 512MiB ws

    // 4x identical idempotent stage1: Delta vs single-launch baseline
    // measures 3*(stage1_dur + node_gap).
    coga_stage1<<<GRID, TPB, 0, stream>>>((const vf4*)x, tgt, partials);
    coga_stage1<<<GRID, TPB, 0, stream>>>((const vf4*)x, tgt, partials);
    coga_stage1<<<GRID, TPB, 0, stream>>>((const vf4*)x, tgt, partials);
    coga_stage1<<<GRID, TPB, 0, stream>>>((const vf4*)x, tgt, partials);
    coga_stage2<<<1, 1024, 0, stream>>>(partials, out);
}

// Round 8
// 193.464 us; speedup vs baseline: 1.4455x; 1.4455x over previous
//
#include <hip/hip_runtime.h>

// N=4194304 rows, C=8. Output: scalar mean(ce_loss * value).
// ROOFLINE ACCOUNTING (R7 measurement round, 4x idempotent stage1):
//   stage1 = (279.7-199.9)/3 ~= 26.6us incl. node gap, vs 23us ideal
//   (144MB @ 6.3TB/s). Timed harness overhead ~170us: d_in restore
//   copyBuffer 77.6us + 512MiB d_ws poison fill 78us + small fills/gaps.
//   Kernel is at the HBM floor; total dur_us ~195 is overhead-dominated.
// Journal: R1 same-address atomics serialize (~160us) -> <=512 atomics.
//   R2-R5: four structures all 200+-4us (structure exonerated).
//   R6: nontemporal loads -5us (read-once stream, don't pollute L2/L3).
//   R7: measured kernel ~26us == floor. This file = best config (R6 fused).

#define N_ROWS 4194304
#define TPB 256
#define GRID 512
#define RPT (N_ROWS / (GRID * TPB))   // 32 rows per thread
#define BATCH 4

typedef float vf4 __attribute__((ext_vector_type(4)));

__device__ __forceinline__ float row_contrib(vf4 v0, vf4 v1, int t) {
    // inv(T_COV) = [[2.4, 1.6],[1.6, 2.4]];  inv(F_COV) = [[10.303,-9.697],[...]]
    // top-2 of logits (exp is monotone -> top-2 of probs)
    float m1 = v0.x, m2 = -INFINITY;
    float xs[7] = {v0.y, v0.z, v0.w, v1.x, v1.y, v1.z, v1.w};
    #pragma unroll
    for (int i = 0; i < 7; ++i) {
        float xi = xs[i];
        float hi = fmaxf(xi, m1);
        float lo = fminf(xi, m1);
        m2 = fmaxf(m2, lo);
        m1 = hi;
    }

    float s = __expf(v0.x - m1) + __expf(v0.y - m1) +
              __expf(v0.z - m1) + __expf(v0.w - m1) +
              __expf(v1.x - m1) + __expf(v1.y - m1) +
              __expf(v1.z - m1) + __expf(v1.w - m1);

    float xt = v0.x;
    xt = (t == 1) ? v0.y : xt;
    xt = (t == 2) ? v0.z : xt;
    xt = (t == 3) ? v0.w : xt;
    xt = (t == 4) ? v1.x : xt;
    xt = (t == 5) ? v1.y : xt;
    xt = (t == 6) ? v1.z : xt;
    xt = (t == 7) ? v1.w : xt;

    float inv_s = 1.0f / s;
    float p_t   = __expf(xt - m1) * inv_s;
    float ce    = (m1 - xt) + __logf(s);     // -logp[target]

    bool  is_t  = (xt == m1);                // p_t is the max prob
    float p_neg = is_t ? __expf(m2 - m1) * inv_s : inv_s;  // max = exp(0)/s

    float aC = is_t ? 2.4f : 10.30303030303030f;
    float bC = is_t ? 1.6f : -9.69696969696970f;
    float dx = p_t   - (is_t ? 0.5f : 0.3f);
    float dy = p_neg - (is_t ? 0.5f : 0.15f);

    float q = aC * (dx * dx + dy * dy) + 2.0f * bC * dx * dy;
    return ce * __expf(-0.5f * q);
}

// Fused: grid-stride, 32 rows/thread batched 4-wide, nontemporal loads,
// block reduce, one atomicAdd per block (512 total).
__global__ __launch_bounds__(TPB) void coga_fused(
    const vf4* __restrict__ x4,
    const int* __restrict__ tgt,
    float* __restrict__ out)
{
    const int tid    = blockIdx.x * TPB + threadIdx.x;
    const int stride = GRID * TPB;

    float acc = 0.0f;
    for (int k = 0; k < RPT; k += BATCH) {
        vf4 a0[BATCH], a1[BATCH];
        int t[BATCH];
        #pragma unroll
        for (int j = 0; j < BATCH; ++j) {
            int row = tid + (k + j) * stride;
            a0[j] = __builtin_nontemporal_load(&x4[2 * (size_t)row]);
            a1[j] = __builtin_nontemporal_load(&x4[2 * (size_t)row + 1]);
            t[j]  = __builtin_nontemporal_load(&tgt[row]);
        }
        #pragma unroll
        for (int j = 0; j < BATCH; ++j)
            acc += row_contrib(a0[j], a1[j], t[j]);
    }

    // wave-64 + LDS block reduction
    #pragma unroll
    for (int off = 32; off > 0; off >>= 1)
        acc += __shfl_down(acc, off, 64);

    __shared__ float wsum[TPB / 64];
    int lane = threadIdx.x & 63;
    int wid  = threadIdx.x >> 6;
    if (lane == 0) wsum[wid] = acc;
    __syncthreads();

    if (threadIdx.x == 0) {
        float bs = 0.0f;
        #pragma unroll
        for (int w = 0; w < TPB / 64; ++w) bs += wsum[w];
        atomicAdd(out, bs * (1.0f / (float)N_ROWS));
    }
}

extern "C" void kernel_launch(void* const* d_in, const int* in_sizes, int n_in,
                              void* d_out, int out_size, void* d_ws, size_t ws_size,
                              hipStream_t stream) {
    const float* x   = (const float*)d_in[0];
    const int*   tgt = (const int*)d_in[1];
    float*       out = (float*)d_out;

    hipMemsetAsync(out, 0, sizeof(float), stream);
    coga_fused<<<GRID, TPB, 0, stream>>>((const vf4*)x, tgt, out);
}